// Round 2
// baseline (1051.754 us; speedup 1.0000x reference)
//
#include <hip/hip_runtime.h>
#include <hip/hip_bf16.h>

// Pipeline:
//  deg[c] += w (atomic)                         -> deg
//  norm[e] = rs(deg[row]) * w * rs(deg[col])    -> norm
//  pre+proj1: h=elu(x*preW+preB) [64]; hWi1=h@Wi1; r1=h@Wr1+b1   -> hW, r
//  memset agg; mp: agg[col*32+l] += norm*hW[row*32+l] (atomic)
//  comb1+proj2: h1=relu(agg+r1); hWi2=h1@Wi2; r2=h1@Wr2+b2       -> hW, r (in place)
//  memset agg; mp again
//  comb2+post: h2=relu(agg+r2); z=h2@postW+postB                 -> z
//  cosine: out[p] = dot(z[ia],z[ib]) / max(|z[ia]||z[ib]|, 1e-6)

#define EPS 1e-6f

__global__ __launch_bounds__(256) void deg_kernel(const int* __restrict__ ei,
                                                  const float* __restrict__ w,
                                                  float* __restrict__ deg, int E) {
    int e = blockIdx.x * 256 + threadIdx.x;
    if (e < E) atomicAdd(&deg[ei[E + e]], w[e]);
}

__global__ __launch_bounds__(256) void norm_kernel(const int* __restrict__ ei,
                                                   const float* __restrict__ w,
                                                   const float* __restrict__ deg,
                                                   float* __restrict__ norm, int E) {
    int e = blockIdx.x * 256 + threadIdx.x;
    if (e >= E) return;
    int r = ei[e], c = ei[E + e];
    float dr = deg[r], dc = deg[c];
    float ir = dr > 0.f ? rsqrtf(dr) : 0.f;
    float ic = dc > 0.f ? rsqrtf(dc) : 0.f;
    norm[e] = ir * w[e] * ic;
}

// pre-MLP (1->64, ELU) fused with both g1 projections (64->32 each).
__global__ __launch_bounds__(256) void pre_kernel(const float* __restrict__ x,
                                                  const float* __restrict__ preW,
                                                  const float* __restrict__ preB,
                                                  const float* __restrict__ Wi,
                                                  const float* __restrict__ Wr,
                                                  const float* __restrict__ b,
                                                  float* __restrict__ hW,
                                                  float* __restrict__ r, int N) {
    __shared__ float sW[64], sB[64], sWi[64 * 32], sWr[64 * 32], sb[32];
    for (int i = threadIdx.x; i < 64; i += 256) { sW[i] = preW[i]; sB[i] = preB[i]; }
    for (int i = threadIdx.x; i < 64 * 32; i += 256) { sWi[i] = Wi[i]; sWr[i] = Wr[i]; }
    if (threadIdx.x < 32) sb[threadIdx.x] = b[threadIdx.x];
    __syncthreads();
    int n = blockIdx.x * 256 + threadIdx.x;
    if (n >= N) return;
    float xv = x[n];
    float accI[32], accR[32];
#pragma unroll
    for (int k = 0; k < 32; k++) { accI[k] = 0.f; accR[k] = sb[k]; }
    for (int j = 0; j < 64; j++) {
        float hj = fmaf(xv, sW[j], sB[j]);
        hj = hj > 0.f ? hj : (expf(hj) - 1.f);   // ELU
#pragma unroll
        for (int k = 0; k < 32; k++) {
            accI[k] = fmaf(hj, sWi[j * 32 + k], accI[k]);
            accR[k] = fmaf(hj, sWr[j * 32 + k], accR[k]);
        }
    }
    float4* hW4 = (float4*)(hW + (size_t)n * 32);
    float4* r4  = (float4*)(r  + (size_t)n * 32);
#pragma unroll
    for (int k = 0; k < 8; k++) {
        hW4[k] = make_float4(accI[4 * k], accI[4 * k + 1], accI[4 * k + 2], accI[4 * k + 3]);
        r4[k]  = make_float4(accR[4 * k], accR[4 * k + 1], accR[4 * k + 2], accR[4 * k + 3]);
    }
}

// message pass: 32 lanes per edge; agg[col*32+lane] += norm[e] * hW[row*32+lane]
__global__ __launch_bounds__(256) void mp_kernel(const float* __restrict__ hW,
                                                 const float* __restrict__ norm,
                                                 const int* __restrict__ ei,
                                                 float* __restrict__ agg, int E) {
    unsigned tid = blockIdx.x * 256u + threadIdx.x;
    unsigned e = tid >> 5;
    unsigned lane = tid & 31;
    if (e >= (unsigned)E) return;
    int row = ei[e], col = ei[E + e];
    float v = norm[e] * hW[(size_t)row * 32 + lane];
    atomicAdd(&agg[(size_t)col * 32 + lane], v);
}

// combine (relu(agg + r)) fused with the next layer's two 32->32 projections.
__global__ __launch_bounds__(256) void comb_kernel(const float* __restrict__ agg,
                                                   float* __restrict__ hW,
                                                   float* __restrict__ r,
                                                   const float* __restrict__ Wi,
                                                   const float* __restrict__ Wr,
                                                   const float* __restrict__ b, int N) {
    __shared__ float sWi[32 * 32], sWr[32 * 32], sb[32];
    for (int i = threadIdx.x; i < 32 * 32; i += 256) { sWi[i] = Wi[i]; sWr[i] = Wr[i]; }
    if (threadIdx.x < 32) sb[threadIdx.x] = b[threadIdx.x];
    __syncthreads();
    int n = blockIdx.x * 256 + threadIdx.x;
    if (n >= N) return;
    float h1[32];
#pragma unroll
    for (int j = 0; j < 32; j++) {
        float v = agg[(size_t)n * 32 + j] + r[(size_t)n * 32 + j];
        h1[j] = v > 0.f ? v : 0.f;   // relu (elu(relu(x)) == relu(x))
    }
    float accI[32], accR[32];
#pragma unroll
    for (int k = 0; k < 32; k++) { accI[k] = 0.f; accR[k] = sb[k]; }
    for (int j = 0; j < 32; j++) {
#pragma unroll
        for (int k = 0; k < 32; k++) {
            accI[k] = fmaf(h1[j], sWi[j * 32 + k], accI[k]);
            accR[k] = fmaf(h1[j], sWr[j * 32 + k], accR[k]);
        }
    }
    float4* hW4 = (float4*)(hW + (size_t)n * 32);
    float4* r4  = (float4*)(r  + (size_t)n * 32);
#pragma unroll
    for (int k = 0; k < 8; k++) {
        hW4[k] = make_float4(accI[4 * k], accI[4 * k + 1], accI[4 * k + 2], accI[4 * k + 3]);
        r4[k]  = make_float4(accR[4 * k], accR[4 * k + 1], accR[4 * k + 2], accR[4 * k + 3]);
    }
}

// final combine + post linear 32->16 -> z
__global__ __launch_bounds__(256) void post_kernel(const float* __restrict__ agg,
                                                   const float* __restrict__ r,
                                                   const float* __restrict__ W,
                                                   const float* __restrict__ b,
                                                   float* __restrict__ z, int N) {
    __shared__ float sW[32 * 16], sb[16];
    for (int i = threadIdx.x; i < 32 * 16; i += 256) sW[i] = W[i];
    if (threadIdx.x < 16) sb[threadIdx.x] = b[threadIdx.x];
    __syncthreads();
    int n = blockIdx.x * 256 + threadIdx.x;
    if (n >= N) return;
    float h2[32];
#pragma unroll
    for (int j = 0; j < 32; j++) {
        float v = agg[(size_t)n * 32 + j] + r[(size_t)n * 32 + j];
        h2[j] = v > 0.f ? v : 0.f;
    }
    float acc[16];
#pragma unroll
    for (int k = 0; k < 16; k++) acc[k] = sb[k];
    for (int j = 0; j < 32; j++) {
#pragma unroll
        for (int k = 0; k < 16; k++) acc[k] = fmaf(h2[j], sW[j * 16 + k], acc[k]);
    }
    float4* z4 = (float4*)(z + (size_t)n * 16);
#pragma unroll
    for (int k = 0; k < 4; k++)
        z4[k] = make_float4(acc[4 * k], acc[4 * k + 1], acc[4 * k + 2], acc[4 * k + 3]);
}

// cosine similarity: 16 lanes per label pair
__global__ __launch_bounds__(256) void cos_kernel(const float* __restrict__ z,
                                                  const int* __restrict__ eli,
                                                  float* __restrict__ out, int L) {
    unsigned tid = blockIdx.x * 256u + threadIdx.x;
    unsigned p = tid >> 4;
    unsigned lane = tid & 15;
    if (p >= (unsigned)L) return;
    int ia = eli[p], ib = eli[L + p];
    float a = z[(size_t)ia * 16 + lane];
    float bb = z[(size_t)ib * 16 + lane];
    float num = a * bb, na = a * a, nb = bb * bb;
#pragma unroll
    for (int off = 8; off; off >>= 1) {
        num += __shfl_xor(num, off);
        na  += __shfl_xor(na, off);
        nb  += __shfl_xor(nb, off);
    }
    if (lane == 0) out[p] = num / fmaxf(sqrtf(na) * sqrtf(nb), EPS);
}

extern "C" void kernel_launch(void* const* d_in, const int* in_sizes, int n_in,
                              void* d_out, int out_size, void* d_ws, size_t ws_size,
                              hipStream_t stream) {
    const float* x     = (const float*)d_in[0];
    const int*   ei    = (const int*)d_in[1];
    const float* ew    = (const float*)d_in[2];
    const int*   eli   = (const int*)d_in[3];
    const float* preW  = (const float*)d_in[4];
    const float* preB  = (const float*)d_in[5];
    const float* g1Wi  = (const float*)d_in[6];
    const float* g1Wr  = (const float*)d_in[7];
    const float* g1b   = (const float*)d_in[8];
    const float* g2Wi  = (const float*)d_in[9];
    const float* g2Wr  = (const float*)d_in[10];
    const float* g2b   = (const float*)d_in[11];
    const float* postW = (const float*)d_in[12];
    const float* postB = (const float*)d_in[13];
    float* out = (float*)d_out;

    const int N = in_sizes[0];          // 100000
    const int E = in_sizes[2];          // 3200000
    const int L = in_sizes[3] / 2;      // 500000

    float* ws = (float*)d_ws;
    size_t off = 0;
    auto alloc = [&](size_t nelem) { float* p = ws + off; off += (nelem + 63) & ~63ull; return p; };
    float* deg  = alloc(N);
    float* norm = alloc(E);
    float* hW   = alloc((size_t)N * 32);
    float* r    = alloc((size_t)N * 32);
    float* agg  = alloc((size_t)N * 32);
    float* z    = alloc((size_t)N * 16);

    const int eb = (E + 255) / 256;
    const int nb = (N + 255) / 256;

    hipMemsetAsync(deg, 0, (size_t)N * sizeof(float), stream);
    deg_kernel<<<eb, 256, 0, stream>>>(ei, ew, deg, E);
    norm_kernel<<<eb, 256, 0, stream>>>(ei, ew, deg, norm, E);

    pre_kernel<<<nb, 256, 0, stream>>>(x, preW, preB, g1Wi, g1Wr, g1b, hW, r, N);

    hipMemsetAsync(agg, 0, (size_t)N * 32 * sizeof(float), stream);
    mp_kernel<<<(int)(((size_t)E * 32 + 255) / 256), 256, 0, stream>>>(hW, norm, ei, agg, E);
    comb_kernel<<<nb, 256, 0, stream>>>(agg, hW, r, g2Wi, g2Wr, g2b, N);

    hipMemsetAsync(agg, 0, (size_t)N * 32 * sizeof(float), stream);
    mp_kernel<<<(int)(((size_t)E * 32 + 255) / 256), 256, 0, stream>>>(hW, norm, ei, agg, E);
    post_kernel<<<nb, 256, 0, stream>>>(agg, r, postW, postB, z, N);

    cos_kernel<<<(int)(((size_t)L * 16 + 255) / 256), 256, 0, stream>>>(z, eli, out, L);
}